// Round 1
// baseline (441.182 us; speedup 1.0000x reference)
//
#include <hip/hip_runtime.h>

// LIF neuron forward scan.
// x: [B=64, F=2048, T=512] f32, scan over contiguous T axis.
//   v = v + (x_t - v) * (DT/TAU);  s = (v >= 1); v *= (1 - s)
// Strategy: 256 rows/block, T chunked by 64, LDS transpose tile[t][row]
// with XOR swizzle (tile[c][r^c]) so both the coalesced staging phase and
// the per-thread sequential scan are LDS-bank-conflict-free.

#define T_LEN 512
#define CHUNK 64
#define ROWS 256
#define NCHUNK (T_LEN / CHUNK)

__global__ __launch_bounds__(256, 2)
void lif_kernel(const float* __restrict__ x, float* __restrict__ out) {
    __shared__ float tile[CHUNK][ROWS];   // 64 KB, XOR-swizzled columns
    const int tid  = threadIdx.x;
    const int row0 = blockIdx.x * ROWS;
    const float k = 1.0f / 20.0f;         // DT / TAU
    float v = 0.0f;                       // membrane potential, carried across chunks

    for (int ch = 0; ch < NCHUNK; ++ch) {
        const int t0 = ch * CHUNK;

        // ---- coalesced global -> LDS (swizzled) ----
        // 4096 float4 elems per tile; 16 per thread. Lanes 0..15 cover one
        // row's 64 floats contiguously -> 1KB/wave per instruction.
        #pragma unroll
        for (int p = 0; p < 16; ++p) {
            const int q = p * 256 + tid;
            const int r = q >> 4;           // row within block tile
            const int c = (q & 15) * 4;     // t offset within chunk
            const float4 val = *reinterpret_cast<const float4*>(
                x + (size_t)(row0 + r) * T_LEN + t0 + c);
            tile[c + 0][r ^ (c + 0)] = val.x;
            tile[c + 1][r ^ (c + 1)] = val.y;
            tile[c + 2][r ^ (c + 2)] = val.z;
            tile[c + 3][r ^ (c + 3)] = val.w;
        }
        __syncthreads();

        // ---- per-row sequential LIF scan (thread tid owns row row0+tid) ----
        #pragma unroll
        for (int t = 0; t < CHUNK; ++t) {
            const float xv = tile[t][tid ^ t];
            v = v + (xv - v) * k;
            const bool fire = (v >= 1.0f);
            tile[t][tid ^ t] = fire ? 1.0f : 0.0f;  // spike out, in place
            v = fire ? 0.0f : v;                    // hard reset
        }
        __syncthreads();

        // ---- coalesced LDS -> global ----
        #pragma unroll
        for (int p = 0; p < 16; ++p) {
            const int q = p * 256 + tid;
            const int r = q >> 4;
            const int c = (q & 15) * 4;
            float4 val;
            val.x = tile[c + 0][r ^ (c + 0)];
            val.y = tile[c + 1][r ^ (c + 1)];
            val.z = tile[c + 2][r ^ (c + 2)];
            val.w = tile[c + 3][r ^ (c + 3)];
            *reinterpret_cast<float4*>(
                out + (size_t)(row0 + r) * T_LEN + t0 + c) = val;
        }
        __syncthreads();
    }
}

extern "C" void kernel_launch(void* const* d_in, const int* in_sizes, int n_in,
                              void* d_out, int out_size, void* d_ws, size_t ws_size,
                              hipStream_t stream) {
    const float* x = (const float*)d_in[0];
    float* out = (float*)d_out;
    const int rows = in_sizes[0] / T_LEN;          // B*F = 131072
    const int grid = rows / ROWS;                  // 512 blocks
    lif_kernel<<<dim3(grid), dim3(ROWS), 0, stream>>>(x, out);
}